// Round 4
// baseline (443.213 us; speedup 1.0000x reference)
//
#include <hip/hip_runtime.h>

namespace {

constexpr int kB  = 16;
constexpr int kNC = 31;
constexpr int kNX = 256;   // rows (H)
constexpr int kNY = 256;   // cols (W)
constexpr int kNO = 3;
constexpr int kKS = 17;
constexpr int NOC = kNO * kNC;   // 93

constexpr int TX = 64;           // output cols per block
constexpr int TY = 64;           // output rows per block
constexpr int HTY = TY + 8;      // 72 staged rows (halo +-4)

// v5 LDS geometry: rows packed with ALTERNATING strides 21/22 16B-slots
// (43 slots per row pair). Rationale: the b128 read conflicts come from
// quad lanes {l,l+16,l+32,l+48} = same tx, rows differing by 4; their bank
// group offset is 4*S mod 8 which is 0 or 4 for ANY linear pitch S. With
// base(r) = (43r - (r&1))/2, rows r,r+4,r+8,r+12 sit at group offsets
// {0,6,4,2} -> 4 distinct groups, conflict-free quads. The tile stays
// byte-linear in slot index (slot l <-> byte 16l), so the global_load_lds
// DMA destination is still legal; source gx and read addresses use the SAME
// geometry (both-sides-or-neither).
constexpr int SLOT_PAIR = 43;                // slots per 2 rows
constexpr int NSLOT = (HTY / 2) * SLOT_PAIR; // 1548 16B slots per tile
constexpr int NSTG  = (NSLOT + 255) / 256;   // 7 issues per thread
constexpr int TILEF = NSLOT * 4;             // 6192 floats per buffer

constexpr int W12 = 12;          // weight row stride (taps 0..8 used, 9..11 pad)

// ---------------------------------------------------------------------------
// prep: w9[row][t] = relu(vk[row*9+t]) stored at stride 12 (16B-aligned rows,
// taps 9..11 zero). soTab[oc] = full shift so = cx-4 in [0,8]; kernel splits
// it into soa = so & ~3 (staging shift) and rs = so & 3 (compile-time arm).
// ---------------------------------------------------------------------------
__global__ void prep(const float* __restrict__ vk, const int* __restrict__ loc,
                     float* __restrict__ w9, int* __restrict__ soTab)
{
    int i = blockIdx.x * 256 + threadIdx.x;
    if (i < NOC * 9 * W12) {
        int row = i / W12;             // row = oc*9 + dy
        int dp  = i - row * W12;       // tap in [0,12)
        float v = 0.0f;
        if (dp < 9) {
            float t = vk[row * 9 + dp];
            v = t > 0.0f ? t : 0.0f;
        }
        w9[i] = v;
    }
    if (i < NOC) {
        // locations[oc*81] = ((oc*17 + 4)*17) + cx - 4  ->  so = cx - 4
        soTab[i] = loc[i * 81] - (i * kKS + 4) * kKS;   // in [0,8]
    }
}

// Per-channel compute with the residual shift RS as a compile-time constant:
// out[jj] += sum_t w9[t] * xr[jj + RS + t], t = 0..8. Max index 3+3+8 = 14,
// so the same 4x ds_read_b128 window covers every RS. RS==0 needs only 12
// floats -> skips the 4th read.
// p0 = xt + 344*ty + xo; row m sits at float offset 4*B(m), B(m)=(43m-(m&1))/2.
template<int RS>
__device__ __forceinline__ void compute_channel(const float* __restrict__ p0,
                                                const float* __restrict__ wch,
                                                float acc[4][4])
{
    #pragma unroll
    for (int m = 0; m < 12; ++m) {
        const int bf = (((43 * m - (m & 1)) >> 1) << 2);   // folds per m
        const float* p = p0 + bf;                          // 16B aligned
        const float4 q0 = *(const float4*)(p);
        const float4 q1 = *(const float4*)(p + 4);
        const float4 q2 = *(const float4*)(p + 8);
        float4 q3 = make_float4(0.f, 0.f, 0.f, 0.f);
        if (RS > 0) q3 = *(const float4*)(p + 12);
        const float xr[16] = { q0.x, q0.y, q0.z, q0.w,
                               q1.x, q1.y, q1.z, q1.w,
                               q2.x, q2.y, q2.z, q2.w,
                               q3.x, q3.y, q3.z, q3.w };

        #pragma unroll
        for (int jr = 0; jr < 4; ++jr) {
            const int dy = m - jr;
            if (dy < 0 || dy >= 9) continue;           // folds at compile time
            const float* wrp = wch + dy * W12;         // block-uniform -> s_load
            const float4 wa = *(const float4*)(wrp);
            const float4 wb = *(const float4*)(wrp + 4);
            const float  w8 = wrp[8];

            #pragma unroll
            for (int jj = 0; jj < 4; ++jj) {
                float a = acc[jr][jj];
                a = fmaf(wa.x, xr[jj + RS + 0], a);
                a = fmaf(wa.y, xr[jj + RS + 1], a);
                a = fmaf(wa.z, xr[jj + RS + 2], a);
                a = fmaf(wa.w, xr[jj + RS + 3], a);
                a = fmaf(wb.x, xr[jj + RS + 4], a);
                a = fmaf(wb.y, xr[jj + RS + 5], a);
                a = fmaf(wb.z, xr[jj + RS + 6], a);
                a = fmaf(wb.w, xr[jj + RS + 7], a);
                a = fmaf(w8,   xr[jj + RS + 8], a);
                acc[jr][jj] = a;
            }
        }
    }
}

// One (batch, order, 64x64 tile) per block. 256 threads as 16x16: each thread
// owns 4 cols x 4 rows. Tile staged pre-shifted by soa via global_load_lds
// (byte-linear dest), double-buffered, one barrier per channel. Residual
// shift rs handled by 4 compile-time arms reading a shifted register window.
__global__ __launch_bounds__(256, 3)
void disperse_conv(const float* __restrict__ x,
                   const float* __restrict__ w9,
                   const int* __restrict__ soTab,
                   float* __restrict__ out)
{
    __shared__ __align__(16) float xtile[2][TILEF];      // 2 x 24,768 B

    const int tid = threadIdx.x;
    const int x0 = blockIdx.x * TX;
    const int y0 = blockIdx.y * TY;
    const int bz = blockIdx.z;         // 48, order-adjacent: bz = b*3 + o
    const int b  = bz / 3;             // -> 3 orders of same (b,tile) run
    const int o  = bz - 3 * b;         //    together, L2/L3 absorbs x re-read

    const int tx = tid & 15;           // 16 threads across x
    const int ty = tid >> 4;           // 16 threads down y
    const int xo = tx * 4;             // 4 consecutive output cols per thread
    const int wv = tid >> 6;           // wave id 0..3 (for uniform LDS base)

    const float* xb = x + (size_t)b * kNC * kNX * kNY;
    const int* soO  = soTab + o * kNC;
    const float* wO = w9 + (size_t)(o * kNC) * 9 * W12;

    // ---- stage channel c into buffer nb: 7 DMA issues per thread ----
    // slot l: pair = l/43, rem = l%43; row r = 2*pair + (rem>=21),
    // col mc = rem - 21*(rem>=21). LDS byte = l*16 (linear). Slot (r,mc)
    // holds x[y0-4+r][x0+soa-8+4*mc]; pad cols (mc>18) are loaded but never
    // read. OOB slots: skip DMA, ds_write zeros (disjoint addresses).
    auto stage = [&](int nb, int c) {
        const float* xc = xb + (size_t)c * (kNX * kNY);
        const int soa   = soO[c] & ~3;                 // block-uniform {0,4,8}
        float* dst = &xtile[nb][0];
        #pragma unroll
        for (int it = 0; it < NSTG; ++it) {
            int l    = it * 256 + tid;
            int pair = l / SLOT_PAIR;                  // magic-mul, cheap
            int rem  = l - pair * SLOT_PAIR;
            int hi   = rem >= 21;
            int r    = 2 * pair + hi;
            int mc   = rem - (hi ? 21 : 0);
            int gy = y0 - 4 + r;
            int gx = x0 + soa - 8 + mc * 4;            // multiple of 4
            bool vslot = (l < NSLOT);
            bool ld = vslot && ((unsigned)gy < (unsigned)kNX)
                            && ((unsigned)gx < (unsigned)kNY);
            if (ld) {
                const float* src = xc + gy * kNY + gx;
                __builtin_amdgcn_global_load_lds(
                    (const __attribute__((address_space(1))) void*)src,
                    (__attribute__((address_space(3))) void*)
                        (dst + it * 1024 + wv * 256),  // wave-uniform base
                    16, 0, 0);                         // + lane*16 by HW
            }
            if (vslot && !ld) {                        // zero the OOB slot
                *(float4*)(dst + (size_t)l * 4) = make_float4(0.f, 0.f, 0.f, 0.f);
            }
        }
    };

    float acc[4][4];
    #pragma unroll
    for (int jr = 0; jr < 4; ++jr)
        #pragma unroll
        for (int jj = 0; jj < 4; ++jj)
            acc[jr][jj] = 0.0f;

    // ---- prologue: kick off channel 0 (latency exposed once) ----
    stage(0, 0);

    for (int c = 0; c < kNC; ++c) {
        // Drains this wave's DMAs for channel c (vmcnt(0)) and makes all
        // waves' DMA results visible; also protects buf[(c+1)&1] before the
        // overwrite below. Nearly free for c>0: latency hid under compute.
        __syncthreads();

        if (c + 1 < kNC)
            stage((c + 1) & 1, c + 1);   // in flight during compute below

        const float* p0  = &xtile[c & 1][0] + 344 * ty + xo;
        const float* wch = wO + (size_t)c * 9 * W12;
        const int rs = soO[c] & 3;                     // block-uniform

        switch (rs) {                                  // scalar branch
            case 0: compute_channel<0>(p0, wch, acc); break;
            case 1: compute_channel<1>(p0, wch, acc); break;
            case 2: compute_channel<2>(p0, wch, acc); break;
            default: compute_channel<3>(p0, wch, acc); break;
        }
    }

    // --- epilogue: 4 rows x 4 cols per thread, aligned float4 stores ---
    #pragma unroll
    for (int jr = 0; jr < 4; ++jr) {
        size_t base = (((size_t)b * kNO + o) * kNX + (size_t)(y0 + ty * 4 + jr)) * kNY
                      + (size_t)(x0 + xo);
        *(float4*)(out + base) = make_float4(acc[jr][0], acc[jr][1],
                                             acc[jr][2], acc[jr][3]);
    }
}

} // namespace

extern "C" void kernel_launch(void* const* d_in, const int* in_sizes, int n_in,
                              void* d_out, int out_size, void* d_ws, size_t ws_size,
                              hipStream_t stream)
{
    const float* x  = (const float*)d_in[0];
    const float* vk = (const float*)d_in[1];
    const int* loc  = (const int*)d_in[2];
    float* outp = (float*)d_out;

    float* w9 = (float*)d_ws;                         // 93*9*12 floats = 40,176 B
    int*   soTab = (int*)(w9 + NOC * 9 * W12);        // 93 ints

    dim3 pgrid((NOC * 9 * W12 + 255) / 256);
    hipLaunchKernelGGL(prep, pgrid, dim3(256), 0, stream, vk, loc, w9, soTab);

    dim3 grid(kNY / TX, kNX / TY, kB * kNO);   // (4, 4, 48) = 768 blocks
    hipLaunchKernelGGL(disperse_conv, grid, dim3(256), 0, stream,
                       x, w9, soTab, outp);
}

// Round 6
// 440.166 us; speedup vs baseline: 1.0069x; 1.0069x over previous
//
#include <hip/hip_runtime.h>

namespace {

constexpr int kB  = 16;
constexpr int kNC = 31;
constexpr int kNX = 256;   // rows (H)
constexpr int kNY = 256;   // cols (W)
constexpr int kNO = 3;
constexpr int kKS = 17;
constexpr int NOC = kNO * kNC;   // 93

// v7: 1-wave blocks (decorrelated pipelines), double-buffered LDS, explicit
// vmcnt fences. v6's corruption: __syncthreads() in a 64-thread block can be
// elided (workgroup == wave) together with its vmcnt drain, so single-buffer
// in-place overwrite raced the in-flight DMAs. Fix: (a) double buffer -- DMA
// never writes the buffer being read; (b) explicit asm s_waitcnt vmcnt(0)
// + sched_barrier(0) fences (cannot be elided / moved across).
constexpr int TX = 32;           // output cols per block
constexpr int TY = 32;           // output rows per block
constexpr int HTY = TY + 8;      // 40 staged rows (halo +-4)
constexpr int XP  = 44;          // pitch (floats) = 11 16B slots; reads reach
                                 // float xo+RS+11 <= 43 = XP-1. Byte-linear.
constexpr int NSLOT = HTY * (XP / 4);        // 440 16B slots per tile
constexpr int NSTG  = (NSLOT + 63) / 64;     // 7 DMA issues per thread
constexpr int TILEF = NSLOT * 4;             // 1760 floats per buffer (7040 B)
constexpr int W12 = 12;          // weight row stride (taps 0..8 used, 9..11 pad)

// ---------------------------------------------------------------------------
// prep: w9[row][t] = relu(vk[row*9+t]) stored at stride 12 (16B-aligned rows,
// taps 9..11 zero). soTab[oc] = full shift so = cx-4 in [0,8]; kernel splits
// it into soa = so & ~3 (staging shift) and rs = so & 3 (compile-time arm).
// ---------------------------------------------------------------------------
__global__ void prep(const float* __restrict__ vk, const int* __restrict__ loc,
                     float* __restrict__ w9, int* __restrict__ soTab)
{
    int i = blockIdx.x * 256 + threadIdx.x;
    if (i < NOC * 9 * W12) {
        int row = i / W12;             // row = oc*9 + dy
        int dp  = i - row * W12;       // tap in [0,12)
        float v = 0.0f;
        if (dp < 9) {
            float t = vk[row * 9 + dp];
            v = t > 0.0f ? t : 0.0f;
        }
        w9[i] = v;
    }
    if (i < NOC) {
        // locations[oc*81] = ((oc*17 + 4)*17) + cx - 4  ->  so = cx - 4
        soTab[i] = loc[i * 81] - (i * kKS + 4) * kKS;   // in [0,8]
    }
}

// Per-channel compute, residual shift RS compile-time. Thread owns 4 cols x
// 4 rows; input rows m=0..11 feed output rows jr=0..3 (dy = m-jr in [0,9)).
// RS==0 needs only 12 floats -> skips the 4th read.
template<int RS>
__device__ __forceinline__ void compute_channel(const float* __restrict__ xt,
                                                const float* __restrict__ wch,
                                                int ty, int xo, float acc[4][4])
{
    #pragma unroll
    for (int m = 0; m < 12; ++m) {
        const int row = ty * 4 + m;
        const float* p = &xt[row * XP + xo];           // 16B aligned
        const float4 q0 = *(const float4*)(p);
        const float4 q1 = *(const float4*)(p + 4);
        const float4 q2 = *(const float4*)(p + 8);
        float4 q3 = make_float4(0.f, 0.f, 0.f, 0.f);
        if (RS > 0) q3 = *(const float4*)(p + 12);
        const float xr[16] = { q0.x, q0.y, q0.z, q0.w,
                               q1.x, q1.y, q1.z, q1.w,
                               q2.x, q2.y, q2.z, q2.w,
                               q3.x, q3.y, q3.z, q3.w };

        #pragma unroll
        for (int jr = 0; jr < 4; ++jr) {
            const int dy = m - jr;
            if (dy < 0 || dy >= 9) continue;           // folds at compile time
            const float* wrp = wch + dy * W12;         // block-uniform -> s_load
            const float4 wa = *(const float4*)(wrp);
            const float4 wb = *(const float4*)(wrp + 4);
            const float  w8 = wrp[8];

            #pragma unroll
            for (int jj = 0; jj < 4; ++jj) {
                float a = acc[jr][jj];
                a = fmaf(wa.x, xr[jj + RS + 0], a);
                a = fmaf(wa.y, xr[jj + RS + 1], a);
                a = fmaf(wa.z, xr[jj + RS + 2], a);
                a = fmaf(wa.w, xr[jj + RS + 3], a);
                a = fmaf(wb.x, xr[jj + RS + 4], a);
                a = fmaf(wb.y, xr[jj + RS + 5], a);
                a = fmaf(wb.z, xr[jj + RS + 6], a);
                a = fmaf(wb.w, xr[jj + RS + 7], a);
                a = fmaf(w8,   xr[jj + RS + 8], a);
                acc[jr][jj] = a;
            }
        }
    }
}

// One (batch, order, 32x32 tile) per 64-thread (1-wave) block. 8 tx (4 cols)
// x 8 ty (4 rows). Double-buffered LDS staged via global_load_lds. Loop:
// drain vmcnt (explicit asm, can't be elided) -> issue next channel's DMAs
// into the OTHER buffer -> compute current buffer. 12 independent 1-wave
// pipelines per CU decorrelate LDS-pipe and VALU usage.
__global__ __launch_bounds__(64, 4)
void disperse_conv(const float* __restrict__ x,
                   const float* __restrict__ w9,
                   const int* __restrict__ soTab,
                   float* __restrict__ out)
{
    __shared__ __align__(16) float xtile[2][TILEF];      // 2 x 7,040 B

    const int tid = threadIdx.x;
    const int x0 = blockIdx.x * TX;
    const int y0 = blockIdx.y * TY;
    const int bz = blockIdx.z;         // 48, order-adjacent: bz = b*3 + o
    const int b  = bz / 3;             // -> 3 orders of same (b,tile) near in
    const int o  = bz - 3 * b;         //    time; L2/L3 absorbs x re-read

    const int tx = tid & 7;            // 8 threads across x
    const int ty = tid >> 3;           // 8 threads down y
    const int xo = tx * 4;             // 4 consecutive output cols per thread

    const float* xb = x + (size_t)b * kNC * kNX * kNY;
    const int* soO  = soTab + o * kNC;
    const float* wO = w9 + (size_t)(o * kNC) * 9 * W12;

    // ---- stage channel c into buffer nb: 7 DMA issues per thread ----
    // slot l = it*64+tid; r = l/11, mc = l%11; LDS byte = l*16 (linear).
    // Slot (r,mc) holds x[y0-4+r][x0+soa-8+4*mc]. OOB slots: skip DMA,
    // ds_write zeros (disjoint addresses -> no ordering hazard with DMA).
    auto stage = [&](int nb, int c) {
        const float* xc = xb + (size_t)c * (kNX * kNY);
        const int soa   = soO[c] & ~3;                 // block-uniform {0,4,8}
        float* dst = &xtile[nb][0];
        #pragma unroll
        for (int it = 0; it < NSTG; ++it) {
            int l  = it * 64 + tid;
            int r  = l / 11;                           // magic-mul, cheap
            int mc = l - r * 11;
            int gy = y0 - 4 + r;
            int gx = x0 + soa - 8 + mc * 4;            // multiple of 4
            bool vslot = (l < NSLOT);
            bool ld = vslot && ((unsigned)gy < (unsigned)kNX)
                            && ((unsigned)gx < (unsigned)kNY);
            if (ld) {
                const float* src = xc + gy * kNY + gx;
                __builtin_amdgcn_global_load_lds(
                    (const __attribute__((address_space(1))) void*)src,
                    (__attribute__((address_space(3))) void*)
                        (dst + it * 256),              // wave-uniform base
                    16, 0, 0);                         // + lane*16 by HW
            }
            if (vslot && !ld) {                        // zero the OOB slot
                *(float4*)(dst + (size_t)l * 4) = make_float4(0.f, 0.f, 0.f, 0.f);
            }
        }
    };

    float acc[4][4];
    #pragma unroll
    for (int jr = 0; jr < 4; ++jr)
        #pragma unroll
        for (int jj = 0; jj < 4; ++jj)
            acc[jr][jj] = 0.0f;

    // ---- prologue: kick off channel 0 into buffer 0 ----
    stage(0, 0);

    for (int c = 0; c < kNC; ++c) {
        // Explicit drain of this wave's DMAs for channel c (buffer c&1).
        // Single wave -> no s_barrier needed; the asm cannot be elided and
        // the "memory" clobber + sched_barriers stop any code motion across.
        __builtin_amdgcn_sched_barrier(0);
        asm volatile("s_waitcnt vmcnt(0)" ::: "memory");
        __builtin_amdgcn_sched_barrier(0);

        // Issue channel c+1 DMAs into the OTHER buffer; they fly during the
        // compute below. WAR safe: buf[(c+1)&1] was last read by compute
        // c-1, fully consumed before this iteration started.
        if (c + 1 < kNC)
            stage((c + 1) & 1, c + 1);
        __builtin_amdgcn_sched_barrier(0);

        const float* xt  = &xtile[c & 1][0];
        const float* wch = wO + (size_t)c * 9 * W12;
        const int rs = soO[c] & 3;                     // block-uniform

        switch (rs) {                                  // scalar branch
            case 0: compute_channel<0>(xt, wch, ty, xo, acc); break;
            case 1: compute_channel<1>(xt, wch, ty, xo, acc); break;
            case 2: compute_channel<2>(xt, wch, ty, xo, acc); break;
            default: compute_channel<3>(xt, wch, ty, xo, acc); break;
        }
    }

    // --- epilogue: 4 rows x 4 cols per thread, aligned float4 stores ---
    #pragma unroll
    for (int jr = 0; jr < 4; ++jr) {
        size_t base = (((size_t)b * kNO + o) * kNX + (size_t)(y0 + ty * 4 + jr)) * kNY
                      + (size_t)(x0 + xo);
        *(float4*)(out + base) = make_float4(acc[jr][0], acc[jr][1],
                                             acc[jr][2], acc[jr][3]);
    }
}

} // namespace

extern "C" void kernel_launch(void* const* d_in, const int* in_sizes, int n_in,
                              void* d_out, int out_size, void* d_ws, size_t ws_size,
                              hipStream_t stream)
{
    const float* x  = (const float*)d_in[0];
    const float* vk = (const float*)d_in[1];
    const int* loc  = (const int*)d_in[2];
    float* outp = (float*)d_out;

    float* w9 = (float*)d_ws;                         // 93*9*12 floats = 40,176 B
    int*   soTab = (int*)(w9 + NOC * 9 * W12);        // 93 ints

    dim3 pgrid((NOC * 9 * W12 + 255) / 256);
    hipLaunchKernelGGL(prep, pgrid, dim3(256), 0, stream, vk, loc, w9, soTab);

    dim3 grid(kNY / TX, kNX / TY, kB * kNO);   // (8, 8, 48) = 3072 blocks
    hipLaunchKernelGGL(disperse_conv, grid, dim3(64), 0, stream,
                       x, w9, soTab, outp);
}